// Round 2
// baseline (574.130 us; speedup 1.0000x reference)
//
#include <hip/hip_runtime.h>
#include <hip/hip_bf16.h>

// SelfAttention non-local block: B=8, C=512, N=4096, CQK=32.  All-MFMA bf16 path.
// v2 pipeline:
//   1. k_cvt_w : Wq/Wk/Wv f32 -> bf16
//   2. k_proj  : fused q/k/v projection straight from x (f32). Per block: 64-n slice,
//                all 576 output rows (512 v-c + 32 q-d + 32 k-d). x columns loaded as
//                B-frags (dword gathers, 64B segments, L1-cached), W rows as A-frags.
//                x is read exactly once from HBM (134 MB). No transpose kernel.
//   3. k_pass1 : L[b][m] = ln(sum_n exp(S[m,n])) via 16x16x32 MFMA (K=32 exact)
//   4. k_pass2 : out = V * exp(S-L). Flash-style: per block 512c x 128n, K-loop over
//                64-m chunks; P produced via MFMA with C-init = -L[m], bf16-packed
//                through LDS (pitch 80 => 16B-aligned b128 reads), consumed as B-frags.
//                acc = 256 VGPRs/wave (unified file, 1 wave/SIMD by design): per-wave
//                tile 128c x 128n halves both LDS-read/MFMA and v-L2/MFMA ratios vs v1.
//                Grid 256 = 1 block/CU; b = blk&7 XCD-swizzle so an XCD's 32 CUs share
//                one batch's v slice (4 MB = L2 size).
// ws: vb 33.5MB | qb 2MB | kb 2MB | Wvb 512KB | Wqb 32KB | Wkb 32KB | L 128KB

typedef __attribute__((ext_vector_type(8))) short s16x8;
typedef __attribute__((ext_vector_type(4))) float f32x4;

#define MFMA16(a, b, c) __builtin_amdgcn_mfma_f32_16x16x32_bf16((a), (b), (c), 0, 0, 0)

__device__ __forceinline__ ushort f2bf(float f) {
  union { float f; unsigned u; } v; v.f = f;
  unsigned r = v.u + 0x7fffu + ((v.u >> 16) & 1u);   // RNE
  return (ushort)(r >> 16);
}

// ---------------- kernel 1: weights -> bf16 ----------------
__global__ void k_cvt_w(const float* __restrict__ Wq, const float* __restrict__ Wk,
                        const float* __restrict__ Wv, ushort* __restrict__ Wqb,
                        ushort* __restrict__ Wkb, ushort* __restrict__ Wvb) {
  int i = blockIdx.x * 256 + threadIdx.x;
  if (i < 262144) Wvb[i] = f2bf(Wv[i]);
  else if (i < 278528) Wqb[i - 262144] = f2bf(Wq[i - 262144]);
  else if (i < 294912) Wkb[i - 278528] = f2bf(Wk[i - 278528]);
}

// ---------------- kernel 2: fused q/k/v projection from x ----------------
// Block: 256 thr / 4 waves, 64-n slice, all M rows. Wave w: v c-tiles [8w,8w+8) plus
// one qk d-tile (w<2 -> q tile w, else k tile w-2). acc = 8*4*4 + 4*4 = 144 regs.
__global__ __launch_bounds__(256, 2) void k_proj(const float* __restrict__ x,
                                                 const ushort* __restrict__ Wqb,
                                                 const ushort* __restrict__ Wkb,
                                                 const ushort* __restrict__ Wvb,
                                                 ushort* __restrict__ qb,
                                                 ushort* __restrict__ kb,
                                                 ushort* __restrict__ vb) {
  const int b = blockIdx.y, n0 = blockIdx.x * 64;
  const int lane = threadIdx.x & 63, w = threadIdx.x >> 6;
  const int quad = lane >> 4, l15 = lane & 15;
  const float* x_b = x + (size_t)b * 512 * 4096;

  const ushort* Wqk = (w < 2) ? (Wqb + (size_t)(w * 16 + l15) * 512)
                              : (Wkb + (size_t)((w - 2) * 16 + l15) * 512);

  f32x4 accv[8][4], accqk[4];
#pragma unroll
  for (int i = 0; i < 8; ++i)
#pragma unroll
    for (int nt = 0; nt < 4; ++nt) accv[i][nt] = {0.f, 0.f, 0.f, 0.f};
#pragma unroll
  for (int nt = 0; nt < 4; ++nt) accqk[nt] = {0.f, 0.f, 0.f, 0.f};

  for (int k0 = 0; k0 < 512; k0 += 32) {
    // B-frags from x columns: lane l15 = n-col, k = k0 + quad*8 + j
    s16x8 bx[4];
#pragma unroll
    for (int nt = 0; nt < 4; ++nt) {
      const float* xc = x_b + (size_t)(k0 + quad * 8) * 4096 + n0 + nt * 16 + l15;
#pragma unroll
      for (int j = 0; j < 8; ++j) bx[nt][j] = (short)f2bf(xc[(size_t)j * 4096]);
    }
    // A-frags from W rows; MFMA
#pragma unroll
    for (int i = 0; i < 8; ++i) {
      s16x8 av = *(const s16x8*)(Wvb + (size_t)((8 * w + i) * 16 + l15) * 512 + k0 + quad * 8);
#pragma unroll
      for (int nt = 0; nt < 4; ++nt) accv[i][nt] = MFMA16(av, bx[nt], accv[i][nt]);
    }
    s16x8 aqk = *(const s16x8*)(Wqk + k0 + quad * 8);
#pragma unroll
    for (int nt = 0; nt < 4; ++nt) accqk[nt] = MFMA16(aqk, bx[nt], accqk[nt]);
  }

  // v store: D layout col=n=l15, row=c=quad*4+r  (scalar bf16 stores, 32B/row segments)
  ushort* vb_b = vb + (size_t)b * 512 * 4096;
#pragma unroll
  for (int i = 0; i < 8; ++i)
#pragma unroll
    for (int nt = 0; nt < 4; ++nt)
#pragma unroll
      for (int r = 0; r < 4; ++r)
        vb_b[(size_t)((8 * w + i) * 16 + quad * 4 + r) * 4096 + n0 + nt * 16 + l15] =
            f2bf(accv[i][nt][r]);

  // q/k store: row m = n-col = l15-based, d = (w&1)*16 + quad*4 + r -> ushort4
  ushort* qk_out = (w < 2) ? (qb + (size_t)b * 4096 * 32) : (kb + (size_t)b * 4096 * 32);
#pragma unroll
  for (int nt = 0; nt < 4; ++nt) {
    ushort4 u;
    u.x = f2bf(accqk[nt][0]); u.y = f2bf(accqk[nt][1]);
    u.z = f2bf(accqk[nt][2]); u.w = f2bf(accqk[nt][3]);
    *(ushort4*)(qk_out + (size_t)(n0 + nt * 16 + l15) * 32 + (w & 1) * 16 + quad * 4) = u;
  }
}

// ---------------- kernel 3: pass1 — L[b][m] = ln(sum_n exp(S[m,n])) ----------------
__global__ __launch_bounds__(256) void k_pass1(const ushort* __restrict__ qb,
                                               const ushort* __restrict__ kb,
                                               float* __restrict__ L) {
  const int b = blockIdx.y, mt = blockIdx.x;
  const int lane = threadIdx.x & 63, w = threadIdx.x >> 6;
  const int quad = lane >> 4, l15 = lane & 15;
  const int m = mt * 64 + w * 16;
  const ushort* qb_b = qb + (size_t)b * 4096 * 32;
  const ushort* kb_b = kb + (size_t)b * 4096 * 32;
  const s16x8 aqf = *(const s16x8*)(qb_b + (size_t)(m + l15) * 32 + quad * 8);
  float ps[4] = {0.f, 0.f, 0.f, 0.f};
  const f32x4 zf = {0.f, 0.f, 0.f, 0.f};
  for (int n0 = 0; n0 < 4096; n0 += 64) {
#pragma unroll
    for (int nt = 0; nt < 4; ++nt) {
      s16x8 bk = *(const s16x8*)(kb_b + (size_t)(n0 + nt * 16 + l15) * 32 + quad * 8);
      f32x4 s = MFMA16(aqf, bk, zf);
#pragma unroll
      for (int r = 0; r < 4; ++r) ps[r] += exp2f(s[r] * 1.4426950408889634f);
    }
  }
  for (int off = 1; off < 16; off <<= 1)
#pragma unroll
    for (int r = 0; r < 4; ++r) ps[r] += __shfl_xor(ps[r], off, 64);
  if (l15 == 0)
#pragma unroll
    for (int r = 0; r < 4; ++r)
      L[(size_t)b * 4096 + m + quad * 4 + r] = log2f(ps[r]) * 0.69314718055994531f;
}

// ---------------- kernel 4: pass2 — out = V @ exp(S - L) ----------------
// Block: 256 thr / 4 waves, tile 512c x 128n, K-loop 64 chunks of 64 m.
// Wave w: c in [128w, 128w+128) (ci=8), all 8 n-tiles. acc = 8*8*4 = 256 VGPRs.
__global__ __launch_bounds__(256, 1) void k_pass2(const ushort* __restrict__ qb,
                                                  const ushort* __restrict__ kb,
                                                  const ushort* __restrict__ vb,
                                                  const float* __restrict__ L,
                                                  float* __restrict__ out) {
  const int blk = blockIdx.x;
  const int b = blk & 7, ntb = blk >> 3;          // XCD-swizzle: one batch per XCD
  const int nbase = ntb * 128;
  const int lane = threadIdx.x & 63, w = threadIdx.x >> 6;
  const int quad = lane >> 4, l15 = lane & 15;
  const int cbase = w * 128;

  __shared__ __align__(16) ushort PT[2][128][80];  // [n][m] bf16, pitch 80 -> 16B-aligned rows

  const ushort* qb_b = qb + (size_t)b * 4096 * 32;
  const ushort* kb_b = kb + (size_t)b * 4096 * 32;
  const ushort* vb_b = vb + (size_t)b * 512 * 4096;
  const float* L_b = L + (size_t)b * 4096;

  // persistent k B-frags: wave w produces n-tiles {2w, 2w+1}
  s16x8 kf[2];
#pragma unroll
  for (int i = 0; i < 2; ++i)
    kf[i] = *(const s16x8*)(kb_b + (size_t)(nbase + (2 * w + i) * 16 + l15) * 32 + quad * 8);

  f32x4 acc[8][8];
#pragma unroll
  for (int ci = 0; ci < 8; ++ci)
#pragma unroll
    for (int nt = 0; nt < 8; ++nt) acc[ci][nt] = {0.f, 0.f, 0.f, 0.f};

  auto produceP = [&](int chunk, int buf) {
    const int m0 = chunk * 64;
#pragma unroll
    for (int mt = 0; mt < 4; ++mt) {
      s16x8 aq = *(const s16x8*)(qb_b + (size_t)(m0 + mt * 16 + l15) * 32 + quad * 8);
      float4 l4 = *(const float4*)(L_b + m0 + mt * 16 + quad * 4);
      f32x4 cin; cin.x = -l4.x; cin.y = -l4.y; cin.z = -l4.z; cin.w = -l4.w;
#pragma unroll
      for (int i = 0; i < 2; ++i) {
        f32x4 s = MFMA16(aq, kf[i], cin);
        ushort4 u;
        u.x = f2bf(__expf(s.x)); u.y = f2bf(__expf(s.y));
        u.z = f2bf(__expf(s.z)); u.w = f2bf(__expf(s.w));
        *(ushort4*)&PT[buf][(2 * w + i) * 16 + l15][mt * 16 + quad * 4] = u;
      }
    }
  };

  produceP(0, 0);
  for (int chunk = 0; chunk < 64; ++chunk) {
    const int m0 = chunk * 64, buf = chunk & 1;
    __syncthreads();
    // v A-frags for this chunk: issue right after barrier so flight overlaps produce
    s16x8 va[8][2];
#pragma unroll
    for (int ci = 0; ci < 8; ++ci) {
      const ushort* vrow = vb_b + (size_t)(cbase + ci * 16 + l15) * 4096 + m0;
      va[ci][0] = *(const s16x8*)(vrow + quad * 8);
      va[ci][1] = *(const s16x8*)(vrow + 32 + quad * 8);
    }
    if (chunk + 1 < 64) produceP(chunk + 1, buf ^ 1);
    // consume P[chunk]
    s16x8 pb[8][2];
#pragma unroll
    for (int nt = 0; nt < 8; ++nt) {
      pb[nt][0] = *(const s16x8*)&PT[buf][nt * 16 + l15][quad * 8];
      pb[nt][1] = *(const s16x8*)&PT[buf][nt * 16 + l15][32 + quad * 8];
    }
#pragma unroll
    for (int ci = 0; ci < 8; ++ci)
#pragma unroll
      for (int nt = 0; nt < 8; ++nt) {
        acc[ci][nt] = MFMA16(va[ci][0], pb[nt][0], acc[ci][nt]);
        acc[ci][nt] = MFMA16(va[ci][1], pb[nt][1], acc[ci][nt]);
      }
  }

  float* out_b = out + (size_t)b * 512 * 4096;
#pragma unroll
  for (int ci = 0; ci < 8; ++ci)
#pragma unroll
    for (int nt = 0; nt < 8; ++nt) {
      const int n = nbase + nt * 16 + l15;
      const int c0 = cbase + ci * 16 + quad * 4;
#pragma unroll
      for (int r = 0; r < 4; ++r) out_b[(size_t)(c0 + r) * 4096 + n] = acc[ci][nt][r];
    }
}

// ---------------- launch ----------------
extern "C" void kernel_launch(void* const* d_in, const int* in_sizes, int n_in,
                              void* d_out, int out_size, void* d_ws, size_t ws_size,
                              hipStream_t stream) {
  const float* x  = (const float*)d_in[0];   // [8,512,64,64]
  const float* Wq = (const float*)d_in[1];   // [32,512]
  const float* Wk = (const float*)d_in[2];   // [32,512]
  const float* Wv = (const float*)d_in[3];   // [512,512]
  float* out = (float*)d_out;                // [8,512,64,64]

  char* ws = (char*)d_ws;
  ushort* vb  = (ushort*)(ws + 0);           // 33,554,432 B
  ushort* qb  = (ushort*)(ws + 33554432);    //  2,097,152 B
  ushort* kb  = (ushort*)(ws + 35651584);    //  2,097,152 B
  ushort* Wvb = (ushort*)(ws + 37748736);    //    524,288 B
  ushort* Wqb = (ushort*)(ws + 38273024);    //     32,768 B
  ushort* Wkb = (ushort*)(ws + 38305792);    //     32,768 B
  float*  Lrs = (float*)(ws + 38338560);     //    131,072 B  (total 38,469,632)

  hipLaunchKernelGGL(k_cvt_w, dim3(1152), dim3(256), 0, stream, Wq, Wk, Wv, Wqb, Wkb, Wvb);
  hipLaunchKernelGGL(k_proj, dim3(64, 8), dim3(256), 0, stream, x, Wqb, Wkb, Wvb, qb, kb, vb);
  hipLaunchKernelGGL(k_pass1, dim3(64, 8), dim3(256), 0, stream, qb, kb, Lrs);
  hipLaunchKernelGGL(k_pass2, dim3(256), dim3(256), 0, stream, qb, kb, vb, Lrs, out);
}

// Round 3
// 417.403 us; speedup vs baseline: 1.3755x; 1.3755x over previous
//
#include <hip/hip_runtime.h>
#include <hip/hip_bf16.h>

// SelfAttention non-local block: B=8, C=512, N=4096, CQK=32.  All-MFMA bf16 path.
// v3:
//  - log2e folded into Wq => S' = S*log2e; softmax via raw v_exp_f32/v_log_f32 (exp2 domain).
//  - bf16 packing via v_perm (3 instr / pair) everywhere; scalar cvt = add+shift.
//  - pass2: block tile 256c x 128n, acc 128 VGPR/wave => 2 waves/SIMD (the v2 256-reg
//    1-wave/SIMD cliff is what caused 391 us). v L2 traffic 1 GB (vs 2 GB v1).
//    P through LDS [n][m] pitch 128B with XOR-granule swizzle (<=2-way conflicts vs 8-way).
//    Single-barrier double buffer; produce split 2m x 2n across waves (kf persistent).
// ws: vb 33.5MB | qb 2MB | kb 2MB | Wvb 512KB | Wqb 32KB | Wkb 32KB | Lneg 128KB

typedef __attribute__((ext_vector_type(8))) short s16x8;
typedef __attribute__((ext_vector_type(4))) float f32x4;

#define MFMA16(a, b, c) __builtin_amdgcn_mfma_f32_16x16x32_bf16((a), (b), (c), 0, 0, 0)

__device__ __forceinline__ ushort f2bf(float f) {   // round-half-up: 2 VALU
  union { float f; unsigned u; } v; v.f = f;
  return (ushort)((v.u + 0x8000u) >> 16);
}
__device__ __forceinline__ unsigned pack_bf16(float lo, float hi) {  // 3 VALU
  union { float f; unsigned u; } a, b; a.f = lo; b.f = hi;
  return __builtin_amdgcn_perm(b.u + 0x8000u, a.u + 0x8000u, 0x07060302u);
}

// ---------------- kernel 1: weights -> bf16 (Wq pre-scaled by log2e) ----------------
__global__ void k_cvt_w(const float* __restrict__ Wq, const float* __restrict__ Wk,
                        const float* __restrict__ Wv, ushort* __restrict__ Wqb,
                        ushort* __restrict__ Wkb, ushort* __restrict__ Wvb) {
  int i = blockIdx.x * 256 + threadIdx.x;
  if (i < 262144) Wvb[i] = f2bf(Wv[i]);
  else if (i < 278528) Wqb[i - 262144] = f2bf(Wq[i - 262144] * 1.4426950408889634f);
  else if (i < 294912) Wkb[i - 278528] = f2bf(Wk[i - 278528]);
}

// ---------------- kernel 2: fused q/k/v projection from x ----------------
__global__ __launch_bounds__(256, 2) void k_proj(const float* __restrict__ x,
                                                 const ushort* __restrict__ Wqb,
                                                 const ushort* __restrict__ Wkb,
                                                 const ushort* __restrict__ Wvb,
                                                 ushort* __restrict__ qb,
                                                 ushort* __restrict__ kb,
                                                 ushort* __restrict__ vb) {
  const int b = blockIdx.y, n0 = blockIdx.x * 64;
  const int lane = threadIdx.x & 63, w = threadIdx.x >> 6;
  const int quad = lane >> 4, l15 = lane & 15;
  const float* x_b = x + (size_t)b * 512 * 4096;

  const ushort* Wqk = (w < 2) ? (Wqb + (size_t)(w * 16 + l15) * 512)
                              : (Wkb + (size_t)((w - 2) * 16 + l15) * 512);

  f32x4 accv[8][4], accqk[4];
#pragma unroll
  for (int i = 0; i < 8; ++i)
#pragma unroll
    for (int nt = 0; nt < 4; ++nt) accv[i][nt] = {0.f, 0.f, 0.f, 0.f};
#pragma unroll
  for (int nt = 0; nt < 4; ++nt) accqk[nt] = {0.f, 0.f, 0.f, 0.f};

  for (int k0 = 0; k0 < 512; k0 += 32) {
    s16x8 bx[4];
#pragma unroll
    for (int nt = 0; nt < 4; ++nt) {
      const float* xc = x_b + (size_t)(k0 + quad * 8) * 4096 + n0 + nt * 16 + l15;
      float f[8];
#pragma unroll
      for (int j = 0; j < 8; ++j) f[j] = xc[(size_t)j * 4096];
      unsigned* bw = (unsigned*)&bx[nt];
#pragma unroll
      for (int jp = 0; jp < 4; ++jp) bw[jp] = pack_bf16(f[2 * jp], f[2 * jp + 1]);
    }
#pragma unroll
    for (int i = 0; i < 8; ++i) {
      s16x8 av = *(const s16x8*)(Wvb + (size_t)((8 * w + i) * 16 + l15) * 512 + k0 + quad * 8);
#pragma unroll
      for (int nt = 0; nt < 4; ++nt) accv[i][nt] = MFMA16(av, bx[nt], accv[i][nt]);
    }
    s16x8 aqk = *(const s16x8*)(Wqk + k0 + quad * 8);
#pragma unroll
    for (int nt = 0; nt < 4; ++nt) accqk[nt] = MFMA16(aqk, bx[nt], accqk[nt]);
  }

  ushort* vb_b = vb + (size_t)b * 512 * 4096;
#pragma unroll
  for (int i = 0; i < 8; ++i)
#pragma unroll
    for (int nt = 0; nt < 4; ++nt)
#pragma unroll
      for (int r = 0; r < 4; ++r)
        vb_b[(size_t)((8 * w + i) * 16 + quad * 4 + r) * 4096 + n0 + nt * 16 + l15] =
            f2bf(accv[i][nt][r]);

  ushort* qk_out = (w < 2) ? (qb + (size_t)b * 4096 * 32) : (kb + (size_t)b * 4096 * 32);
#pragma unroll
  for (int nt = 0; nt < 4; ++nt) {
    ushort4 u;
    u.x = f2bf(accqk[nt][0]); u.y = f2bf(accqk[nt][1]);
    u.z = f2bf(accqk[nt][2]); u.w = f2bf(accqk[nt][3]);
    *(ushort4*)(qk_out + (size_t)(n0 + nt * 16 + l15) * 32 + (w & 1) * 16 + quad * 4) = u;
  }
}

// ---------------- kernel 3: pass1 — Lneg[b][m] = -log2(sum_n 2^(S'[m,n])) ----------------
__global__ __launch_bounds__(256) void k_pass1(const ushort* __restrict__ qb,
                                               const ushort* __restrict__ kb,
                                               float* __restrict__ Lneg) {
  const int b = blockIdx.y, mt = blockIdx.x;
  const int lane = threadIdx.x & 63, w = threadIdx.x >> 6;
  const int quad = lane >> 4, l15 = lane & 15;
  const int m = mt * 64 + w * 16;
  const ushort* qb_b = qb + (size_t)b * 4096 * 32;
  const ushort* kb_b = kb + (size_t)b * 4096 * 32;
  const s16x8 aqf = *(const s16x8*)(qb_b + (size_t)(m + l15) * 32 + quad * 8);
  float ps[4] = {0.f, 0.f, 0.f, 0.f};
  const f32x4 zf = {0.f, 0.f, 0.f, 0.f};
  for (int n0 = 0; n0 < 4096; n0 += 64) {
#pragma unroll
    for (int nt = 0; nt < 4; ++nt) {
      s16x8 bk = *(const s16x8*)(kb_b + (size_t)(n0 + nt * 16 + l15) * 32 + quad * 8);
      f32x4 s = MFMA16(aqf, bk, zf);
#pragma unroll
      for (int r = 0; r < 4; ++r) ps[r] += exp2f(s[r]);
    }
  }
  for (int off = 1; off < 16; off <<= 1)
#pragma unroll
    for (int r = 0; r < 4; ++r) ps[r] += __shfl_xor(ps[r], off, 64);
  if (l15 == 0)
#pragma unroll
    for (int r = 0; r < 4; ++r)
      Lneg[(size_t)b * 4096 + m + quad * 4 + r] = -log2f(ps[r]);
}

// ---------------- kernel 4: pass2 — out = V @ 2^(S' + Lneg) ----------------
// Grid 512 = 8 b (XCD) x 32 ntb x 2 cb. Block 4 waves: tile 256c x 128n, chunk 64 m.
// Wave w: consume c [cb*256+64w, +64) x all 128n (acc 4x8x4=128 VGPR);
//         produce m-tiles {2(w&1),2(w&1)+1} x n-tiles {4(w>>1)..+3} (kf persistent).
__global__ __launch_bounds__(256, 2) void k_pass2(const ushort* __restrict__ qb,
                                                  const ushort* __restrict__ kb,
                                                  const ushort* __restrict__ vb,
                                                  const float* __restrict__ Lneg,
                                                  float* __restrict__ out) {
  const int blk = blockIdx.x;
  const int b = blk & 7, blkb = blk >> 3;
  const int ntb = blkb & 31, cb = blkb >> 5;
  const int nbase = ntb * 128;
  const int lane = threadIdx.x & 63, w = threadIdx.x >> 6;
  const int quad = lane >> 4, l15 = lane & 15;
  const int wm = w & 1, wn = w >> 1;
  const int cbase = cb * 256 + w * 64;
  const int swz = l15 & 7;

  // [buf][n row: 128B = 64 m bf16], granule(16B)-XOR-swizzled by (row&7)
  __shared__ __align__(16) ushort PT[2][128 * 64];

  const ushort* qb_b = qb + (size_t)b * 4096 * 32;
  const ushort* kb_b = kb + (size_t)b * 4096 * 32;
  const ushort* vb_b = vb + (size_t)b * 512 * 4096;
  const float* L_b = Lneg + (size_t)b * 4096;

  s16x8 kf[4];
#pragma unroll
  for (int i = 0; i < 4; ++i)
    kf[i] = *(const s16x8*)(kb_b + (size_t)(nbase + (4 * wn + i) * 16 + l15) * 32 + quad * 8);

  f32x4 acc[4][8];
#pragma unroll
  for (int ci = 0; ci < 4; ++ci)
#pragma unroll
    for (int nt = 0; nt < 8; ++nt) acc[ci][nt] = {0.f, 0.f, 0.f, 0.f};

  auto produceP = [&](int chunk, int buf) {
    const int m0 = chunk * 64;
    char* P = (char*)&PT[buf][0];
#pragma unroll
    for (int j = 0; j < 2; ++j) {
      const int M = 2 * wm + j;
      s16x8 aq = *(const s16x8*)(qb_b + (size_t)(m0 + M * 16 + l15) * 32 + quad * 8);
      float4 l4 = *(const float4*)(L_b + m0 + M * 16 + quad * 4);   // already negative
      f32x4 cin; cin.x = l4.x; cin.y = l4.y; cin.z = l4.z; cin.w = l4.w;
#pragma unroll
      for (int i = 0; i < 4; ++i) {
        const int T = 4 * wn + i;
        f32x4 s = MFMA16(aq, kf[i], cin);                 // S' + Lneg
        uint2 u;
        u.x = pack_bf16(exp2f(s.x), exp2f(s.y));
        u.y = pack_bf16(exp2f(s.z), exp2f(s.w));
        const int row = T * 16 + l15;
        const int gran = (2 * M + (quad >> 1)) ^ swz;
        *(uint2*)(P + row * 128 + gran * 16 + (quad & 1) * 8) = u;
      }
    }
  };

  produceP(0, 0);
  for (int chunk = 0; chunk < 64; ++chunk) {
    const int m0 = chunk * 64, buf = chunk & 1;
    __syncthreads();
    s16x8 va[4][2];
#pragma unroll
    for (int ci = 0; ci < 4; ++ci) {
      const ushort* vrow = vb_b + (size_t)(cbase + ci * 16 + l15) * 4096 + m0;
      va[ci][0] = *(const s16x8*)(vrow + quad * 8);
      va[ci][1] = *(const s16x8*)(vrow + 32 + quad * 8);
    }
    if (chunk + 1 < 64) produceP(chunk + 1, buf ^ 1);
    const char* P = (const char*)&PT[buf][0];
#pragma unroll
    for (int nt = 0; nt < 8; ++nt) {
      const int row = nt * 16 + l15;
      s16x8 p0 = *(const s16x8*)(P + row * 128 + ((quad ^ swz)) * 16);
      s16x8 p1 = *(const s16x8*)(P + row * 128 + (((4 + quad) ^ swz)) * 16);
#pragma unroll
      for (int ci = 0; ci < 4; ++ci) {
        acc[ci][nt] = MFMA16(va[ci][0], p0, acc[ci][nt]);
        acc[ci][nt] = MFMA16(va[ci][1], p1, acc[ci][nt]);
      }
    }
  }

  float* out_b = out + (size_t)b * 512 * 4096;
#pragma unroll
  for (int ci = 0; ci < 4; ++ci)
#pragma unroll
    for (int nt = 0; nt < 8; ++nt) {
      const int n = nbase + nt * 16 + l15;
      const int c0 = cbase + ci * 16 + quad * 4;
#pragma unroll
      for (int r = 0; r < 4; ++r) out_b[(size_t)(c0 + r) * 4096 + n] = acc[ci][nt][r];
    }
}

// ---------------- launch ----------------
extern "C" void kernel_launch(void* const* d_in, const int* in_sizes, int n_in,
                              void* d_out, int out_size, void* d_ws, size_t ws_size,
                              hipStream_t stream) {
  const float* x  = (const float*)d_in[0];   // [8,512,64,64]
  const float* Wq = (const float*)d_in[1];   // [32,512]
  const float* Wk = (const float*)d_in[2];   // [32,512]
  const float* Wv = (const float*)d_in[3];   // [512,512]
  float* out = (float*)d_out;                // [8,512,64,64]

  char* ws = (char*)d_ws;
  ushort* vb  = (ushort*)(ws + 0);           // 33,554,432 B
  ushort* qb  = (ushort*)(ws + 33554432);    //  2,097,152 B
  ushort* kb  = (ushort*)(ws + 35651584);    //  2,097,152 B
  ushort* Wvb = (ushort*)(ws + 37748736);    //    524,288 B
  ushort* Wqb = (ushort*)(ws + 38273024);    //     32,768 B
  ushort* Wkb = (ushort*)(ws + 38305792);    //     32,768 B
  float*  Lrs = (float*)(ws + 38338560);     //    131,072 B

  hipLaunchKernelGGL(k_cvt_w, dim3(1152), dim3(256), 0, stream, Wq, Wk, Wv, Wqb, Wkb, Wvb);
  hipLaunchKernelGGL(k_proj, dim3(64, 8), dim3(256), 0, stream, x, Wqb, Wkb, Wvb, qb, kb, vb);
  hipLaunchKernelGGL(k_pass1, dim3(64, 8), dim3(256), 0, stream, qb, kb, Lrs);
  hipLaunchKernelGGL(k_pass2, dim3(512), dim3(256), 0, stream, qb, kb, vb, Lrs, out);
}

// Round 4
// 388.196 us; speedup vs baseline: 1.4790x; 1.0752x over previous
//
#include <hip/hip_runtime.h>
#include <hip/hip_bf16.h>

// SelfAttention non-local block: B=8, C=512, N=4096, CQK=32.  All-MFMA bf16 path.
// v4:
//  - k_xpose: x [b][c][n] f32 -> xT [b][n][c] bf16. Coalesced 1KB row reads, SoA
//    pair-packed LDS (b32, <=2-way banks), 128B-contiguous writes. Replaces the
//    column-gather in v3's proj (which caused ~170us of segmented HBM reads).
//  - k_proj: reads xT with b128 B-frags (fully coalesced); fused q/k/v.
//  - k_pass2 reorder: per chunk, P ds_reads issue BEFORE produce's ds_writes
//    (lgkmcnt is one in-order queue -- v3 chained consume behind produce's global
//    load + exp + write chain). aq/Lneg prefetched a chunk ahead so produce has
//    zero loads on its critical path; va prefetched after consume.
// ws: vb 33.5MB | xT 33.5MB | qb 2MB | kb 2MB | Wvb 512KB | Wqb 32KB | Wkb 32KB | Lneg 128KB

typedef __attribute__((ext_vector_type(8))) short s16x8;
typedef __attribute__((ext_vector_type(4))) float f32x4;

#define MFMA16(a, b, c) __builtin_amdgcn_mfma_f32_16x16x32_bf16((a), (b), (c), 0, 0, 0)

__device__ __forceinline__ ushort f2bf(float f) {
  union { float f; unsigned u; } v; v.f = f;
  return (ushort)((v.u + 0x8000u) >> 16);
}
__device__ __forceinline__ unsigned pack_bf16(float lo, float hi) {  // (hi<<16)|lo
  union { float f; unsigned u; } a, b; a.f = lo; b.f = hi;
  return __builtin_amdgcn_perm(b.u + 0x8000u, a.u + 0x8000u, 0x07060302u);
}

// ---------------- kernel 1: weights -> bf16 (Wq pre-scaled by log2e) ----------------
__global__ void k_cvt_w(const float* __restrict__ Wq, const float* __restrict__ Wk,
                        const float* __restrict__ Wv, ushort* __restrict__ Wqb,
                        ushort* __restrict__ Wkb, ushort* __restrict__ Wvb) {
  int i = blockIdx.x * 256 + threadIdx.x;
  if (i < 262144) Wvb[i] = f2bf(Wv[i]);
  else if (i < 278528) Wqb[i - 262144] = f2bf(Wq[i - 262144] * 1.4426950408889634f);
  else if (i < 294912) Wkb[i - 278528] = f2bf(Wk[i - 278528]);
}

// ---------------- kernel 2: transpose x -> xT bf16 ----------------
// Tile 64c x 256n. Phase1: float4 row loads (1KB contiguous per row), pack n-pairs,
// SoA LDS U[2][64][65] (even/odd pair split => <=2-way banks). Phase2: 8-lane groups
// build 128B-contiguous xT rows via v_perm extraction.
__global__ __launch_bounds__(256) void k_xpose(const float* __restrict__ x,
                                               ushort* __restrict__ xT) {
  const int b = blockIdx.z, c0 = blockIdx.y * 64, n0 = blockIdx.x * 256;
  __shared__ uint U[2][64][65];
  const int t = threadIdx.x;
  const int wv = t >> 6, ln = t & 63;
  const float* xp = x + ((size_t)b * 512 + c0 + wv * 16) * 4096 + n0 + ln * 4;
#pragma unroll
  for (int i = 0; i < 16; ++i) {
    float4 f = *(const float4*)(xp + (size_t)i * 4096);
    U[0][wv * 16 + i][ln] = pack_bf16(f.x, f.y);   // pairs (4ln,4ln+1)   -> pair idx 2ln
    U[1][wv * 16 + i][ln] = pack_bf16(f.z, f.w);   // pairs (4ln+2,4ln+3) -> pair idx 2ln+1
  }
  __syncthreads();
  const int c_seg = (t & 7) * 8;
#pragma unroll
  for (int pass = 0; pass < 8; ++pass) {
    const int nl = pass * 32 + (t >> 3);
    const int p = nl >> 1;              // pair index
    const int h = p & 1, idx = p >> 1;  // SoA half, slot
    const uint sel = (nl & 1) ? 0x07060302u : 0x05040100u;
    uint o[4];
#pragma unroll
    for (int j = 0; j < 4; ++j) {
      uint ua = U[h][c_seg + 2 * j][idx];
      uint ub = U[h][c_seg + 2 * j + 1][idx];
      o[j] = __builtin_amdgcn_perm(ub, ua, sel);   // (bf(c_odd)<<16)|bf(c_even)
    }
    *(uint4*)(xT + ((size_t)b * 4096 + n0 + nl) * 512 + c0 + c_seg) = *(uint4*)o;
  }
}

// ---------------- kernel 3: fused q/k/v projection from xT ----------------
__global__ __launch_bounds__(256, 2) void k_proj(const ushort* __restrict__ xT,
                                                 const ushort* __restrict__ Wqb,
                                                 const ushort* __restrict__ Wkb,
                                                 const ushort* __restrict__ Wvb,
                                                 ushort* __restrict__ qb,
                                                 ushort* __restrict__ kb,
                                                 ushort* __restrict__ vb) {
  const int b = blockIdx.y, n0 = blockIdx.x * 64;
  const int lane = threadIdx.x & 63, w = threadIdx.x >> 6;
  const int quad = lane >> 4, l15 = lane & 15;
  const ushort* xT_b = xT + (size_t)b * 4096 * 512;

  const ushort* Wqk = (w < 2) ? (Wqb + (size_t)(w * 16 + l15) * 512)
                              : (Wkb + (size_t)((w - 2) * 16 + l15) * 512);

  f32x4 accv[8][4], accqk[4];
#pragma unroll
  for (int i = 0; i < 8; ++i)
#pragma unroll
    for (int nt = 0; nt < 4; ++nt) accv[i][nt] = {0.f, 0.f, 0.f, 0.f};
#pragma unroll
  for (int nt = 0; nt < 4; ++nt) accqk[nt] = {0.f, 0.f, 0.f, 0.f};

  for (int k0 = 0; k0 < 512; k0 += 32) {
    s16x8 bx[4];
#pragma unroll
    for (int nt = 0; nt < 4; ++nt)
      bx[nt] = *(const s16x8*)(xT_b + (size_t)(n0 + nt * 16 + l15) * 512 + k0 + quad * 8);
#pragma unroll
    for (int i = 0; i < 8; ++i) {
      s16x8 av = *(const s16x8*)(Wvb + (size_t)((8 * w + i) * 16 + l15) * 512 + k0 + quad * 8);
#pragma unroll
      for (int nt = 0; nt < 4; ++nt) accv[i][nt] = MFMA16(av, bx[nt], accv[i][nt]);
    }
    s16x8 aqk = *(const s16x8*)(Wqk + k0 + quad * 8);
#pragma unroll
    for (int nt = 0; nt < 4; ++nt) accqk[nt] = MFMA16(aqk, bx[nt], accqk[nt]);
  }

  ushort* vb_b = vb + (size_t)b * 512 * 4096;
#pragma unroll
  for (int i = 0; i < 8; ++i)
#pragma unroll
    for (int nt = 0; nt < 4; ++nt)
#pragma unroll
      for (int r = 0; r < 4; ++r)
        vb_b[(size_t)((8 * w + i) * 16 + quad * 4 + r) * 4096 + n0 + nt * 16 + l15] =
            f2bf(accv[i][nt][r]);

  ushort* qk_out = (w < 2) ? (qb + (size_t)b * 4096 * 32) : (kb + (size_t)b * 4096 * 32);
#pragma unroll
  for (int nt = 0; nt < 4; ++nt) {
    ushort4 u;
    u.x = f2bf(accqk[nt][0]); u.y = f2bf(accqk[nt][1]);
    u.z = f2bf(accqk[nt][2]); u.w = f2bf(accqk[nt][3]);
    *(ushort4*)(qk_out + (size_t)(n0 + nt * 16 + l15) * 32 + (w & 1) * 16 + quad * 4) = u;
  }
}

// ---------------- kernel 4: pass1 — Lneg[b][m] = -log2(sum_n 2^(S'[m,n])) ----------------
__global__ __launch_bounds__(256) void k_pass1(const ushort* __restrict__ qb,
                                               const ushort* __restrict__ kb,
                                               float* __restrict__ Lneg) {
  const int b = blockIdx.y, mt = blockIdx.x;
  const int lane = threadIdx.x & 63, w = threadIdx.x >> 6;
  const int quad = lane >> 4, l15 = lane & 15;
  const int m = mt * 64 + w * 16;
  const ushort* qb_b = qb + (size_t)b * 4096 * 32;
  const ushort* kb_b = kb + (size_t)b * 4096 * 32;
  const s16x8 aqf = *(const s16x8*)(qb_b + (size_t)(m + l15) * 32 + quad * 8);
  float ps[4] = {0.f, 0.f, 0.f, 0.f};
  const f32x4 zf = {0.f, 0.f, 0.f, 0.f};
  for (int n0 = 0; n0 < 4096; n0 += 64) {
#pragma unroll
    for (int nt = 0; nt < 4; ++nt) {
      s16x8 bk = *(const s16x8*)(kb_b + (size_t)(n0 + nt * 16 + l15) * 32 + quad * 8);
      f32x4 s = MFMA16(aqf, bk, zf);
#pragma unroll
      for (int r = 0; r < 4; ++r) ps[r] += exp2f(s[r]);
    }
  }
  for (int off = 1; off < 16; off <<= 1)
#pragma unroll
    for (int r = 0; r < 4; ++r) ps[r] += __shfl_xor(ps[r], off, 64);
  if (l15 == 0)
#pragma unroll
    for (int r = 0; r < 4; ++r)
      Lneg[(size_t)b * 4096 + m + quad * 4 + r] = -log2f(ps[r]);
}

// ---------------- kernel 5: pass2 — out = V @ 2^(S' + Lneg) ----------------
// Grid 512 = 8 b (XCD) x 32 ntb x 2 cb. Block 4 waves: tile 256c x 128n, chunk 64 m.
// Pipeline order per chunk: barrier -> P ds_reads -> produce(next, preloaded aq/l4)
// -> consume -> global prefetches for next chunk.
__global__ __launch_bounds__(256, 2) void k_pass2(const ushort* __restrict__ qb,
                                                  const ushort* __restrict__ kb,
                                                  const ushort* __restrict__ vb,
                                                  const float* __restrict__ Lneg,
                                                  float* __restrict__ out) {
  const int blk = blockIdx.x;
  const int b = blk & 7, blkb = blk >> 3;
  const int ntb = blkb & 31, cb = blkb >> 5;
  const int nbase = ntb * 128;
  const int lane = threadIdx.x & 63, w = threadIdx.x >> 6;
  const int quad = lane >> 4, l15 = lane & 15;
  const int wm = w & 1, wn = w >> 1;
  const int cbase = cb * 256 + w * 64;
  const int swz = l15 & 7;

  __shared__ __align__(16) ushort PT[2][128 * 64];  // [n row: 128B], 16B-granule XOR swizzle

  const ushort* qb_b = qb + (size_t)b * 4096 * 32;
  const ushort* kb_b = kb + (size_t)b * 4096 * 32;
  const ushort* vb_b = vb + (size_t)b * 512 * 4096;
  const float* L_b = Lneg + (size_t)b * 4096;

  s16x8 kf[4];
#pragma unroll
  for (int i = 0; i < 4; ++i)
    kf[i] = *(const s16x8*)(kb_b + (size_t)(nbase + (4 * wn + i) * 16 + l15) * 32 + quad * 8);

  f32x4 acc[4][8];
#pragma unroll
  for (int ci = 0; ci < 4; ++ci)
#pragma unroll
    for (int nt = 0; nt < 8; ++nt) acc[ci][nt] = {0.f, 0.f, 0.f, 0.f};

  s16x8 aqp[2];    // prefetched q A-frags for next produce (2 m-tiles)
  float4 l4p[2];   // prefetched Lneg
  s16x8 va[4][2];  // prefetched v A-frags for current chunk

  auto loadQ = [&](int chunk) {
    const int m0 = chunk * 64;
#pragma unroll
    for (int j = 0; j < 2; ++j) {
      const int M = 2 * wm + j;
      aqp[j] = *(const s16x8*)(qb_b + (size_t)(m0 + M * 16 + l15) * 32 + quad * 8);
      l4p[j] = *(const float4*)(L_b + m0 + M * 16 + quad * 4);
    }
  };
  auto loadV = [&](int chunk) {
    const int m0 = chunk * 64;
#pragma unroll
    for (int ci = 0; ci < 4; ++ci) {
      const ushort* vrow = vb_b + (size_t)(cbase + ci * 16 + l15) * 4096 + m0;
      va[ci][0] = *(const s16x8*)(vrow + quad * 8);
      va[ci][1] = *(const s16x8*)(vrow + 32 + quad * 8);
    }
  };
  auto produceP = [&](int buf) {   // uses aqp/l4p (no loads on critical path)
    char* P = (char*)&PT[buf][0];
#pragma unroll
    for (int j = 0; j < 2; ++j) {
      const int M = 2 * wm + j;
      f32x4 cin; cin.x = l4p[j].x; cin.y = l4p[j].y; cin.z = l4p[j].z; cin.w = l4p[j].w;
#pragma unroll
      for (int i = 0; i < 4; ++i) {
        const int T = 4 * wn + i;
        f32x4 s = MFMA16(aqp[j], kf[i], cin);             // S' + Lneg
        uint2 u;
        u.x = pack_bf16(exp2f(s.x), exp2f(s.y));
        u.y = pack_bf16(exp2f(s.z), exp2f(s.w));
        const int row = T * 16 + l15;
        const int gran = (2 * M + (quad >> 1)) ^ swz;
        *(uint2*)(P + row * 128 + gran * 16 + (quad & 1) * 8) = u;
      }
    }
  };

  loadQ(0);
  produceP(0);
  loadQ(1);
  loadV(0);

  for (int chunk = 0; chunk < 64; ++chunk) {
    const int buf = chunk & 1;
    __syncthreads();
    const char* P = (const char*)&PT[buf][0];
    // --- first-half P reads (issued before any ds_write of this iteration) ---
    s16x8 p0[4], p1[4];
#pragma unroll
    for (int nt = 0; nt < 4; ++nt) {
      const int row = nt * 16 + l15;
      p0[nt] = *(const s16x8*)(P + row * 128 + (quad ^ swz) * 16);
      p1[nt] = *(const s16x8*)(P + row * 128 + ((4 + quad) ^ swz) * 16);
    }
    // --- produce next chunk into other buffer (pure compute + ds_write) ---
    if (chunk < 63) produceP(buf ^ 1);
    if (chunk < 62) loadQ(chunk + 2);
    // --- consume first half ---
#pragma unroll
    for (int nt = 0; nt < 4; ++nt)
#pragma unroll
      for (int ci = 0; ci < 4; ++ci) {
        acc[ci][nt] = MFMA16(va[ci][0], p0[nt], acc[ci][nt]);
        acc[ci][nt] = MFMA16(va[ci][1], p1[nt], acc[ci][nt]);
      }
    // --- second-half P reads + consume ---
    s16x8 r0[4], r1[4];
#pragma unroll
    for (int nt = 0; nt < 4; ++nt) {
      const int row = (nt + 4) * 16 + l15;
      r0[nt] = *(const s16x8*)(P + row * 128 + (quad ^ swz) * 16);
      r1[nt] = *(const s16x8*)(P + row * 128 + ((4 + quad) ^ swz) * 16);
    }
#pragma unroll
    for (int nt = 0; nt < 4; ++nt)
#pragma unroll
      for (int ci = 0; ci < 4; ++ci) {
        acc[ci][nt + 4] = MFMA16(va[ci][0], r0[nt], acc[ci][nt + 4]);
        acc[ci][nt + 4] = MFMA16(va[ci][1], r1[nt], acc[ci][nt + 4]);
      }
    // --- prefetch next chunk's v ---
    if (chunk < 63) loadV(chunk + 1);
  }

  float* out_b = out + (size_t)b * 512 * 4096;
#pragma unroll
  for (int ci = 0; ci < 4; ++ci)
#pragma unroll
    for (int nt = 0; nt < 8; ++nt) {
      const int n = nbase + nt * 16 + l15;
      const int c0 = cbase + ci * 16 + quad * 4;
#pragma unroll
      for (int r = 0; r < 4; ++r) out_b[(size_t)(c0 + r) * 4096 + n] = acc[ci][nt][r];
    }
}

// ---------------- launch ----------------
extern "C" void kernel_launch(void* const* d_in, const int* in_sizes, int n_in,
                              void* d_out, int out_size, void* d_ws, size_t ws_size,
                              hipStream_t stream) {
  const float* x  = (const float*)d_in[0];   // [8,512,64,64]
  const float* Wq = (const float*)d_in[1];   // [32,512]
  const float* Wk = (const float*)d_in[2];   // [32,512]
  const float* Wv = (const float*)d_in[3];   // [512,512]
  float* out = (float*)d_out;                // [8,512,64,64]

  char* ws = (char*)d_ws;
  ushort* vb  = (ushort*)(ws + 0);           // 33,554,432 B
  ushort* xT  = (ushort*)(ws + 33554432);    // 33,554,432 B
  ushort* qb  = (ushort*)(ws + 67108864);    //  2,097,152 B
  ushort* kb  = (ushort*)(ws + 69206016);    //  2,097,152 B
  ushort* Wvb = (ushort*)(ws + 71303168);    //    524,288 B
  ushort* Wqb = (ushort*)(ws + 71827456);    //     32,768 B
  ushort* Wkb = (ushort*)(ws + 71860224);    //     32,768 B
  float*  Lrs = (float*)(ws + 71892992);     //    131,072 B  (total 72,024,064)

  hipLaunchKernelGGL(k_cvt_w, dim3(1152), dim3(256), 0, stream, Wq, Wk, Wv, Wqb, Wkb, Wvb);
  hipLaunchKernelGGL(k_xpose, dim3(16, 8, 8), dim3(256), 0, stream, x, xT);
  hipLaunchKernelGGL(k_proj, dim3(64, 8), dim3(256), 0, stream, xT, Wqb, Wkb, Wvb, qb, kb, vb);
  hipLaunchKernelGGL(k_pass1, dim3(64, 8), dim3(256), 0, stream, qb, kb, Lrs);
  hipLaunchKernelGGL(k_pass2, dim3(512), dim3(256), 0, stream, qb, kb, vb, Lrs, out);
}